// Round 1
// baseline (535.975 us; speedup 1.0000x reference)
//
#include <hip/hip_runtime.h>

// ReactionTerm: y_out[b, inds_1p[r]] += y_in[b, inds_1r[r]] * rates_1st[b, r]
//               y_out[b, inds_2p[r]] += y_in[b, i2r0[r]] * y_in[b, i2r1[r]] * rates_2nd[b, r]
// B=1024 rows, N_SPEC=2048 species, R1=20000, R2=40000.
// One block per row; y row + accumulator row both live in LDS (16 KB/block).
// All rate reads are coalesced streaming; scatter goes through LDS float atomics.

#define B_DIM 1024
#define N_SPEC 2048
#define R1 20000
#define R2 40000
#define BLOCK 256

__global__ __launch_bounds__(BLOCK) void ReactionTerm_kernel(
    const float* __restrict__ y_in,       // [B, N_SPEC]
    const float* __restrict__ rates_1st,  // [B, R1]
    const float* __restrict__ rates_2nd,  // [B, R2]
    const int*   __restrict__ inds_1r,    // [R1]
    const int*   __restrict__ inds_1p,    // [R1]
    const int*   __restrict__ inds_2r,    // [R2, 2]
    const int*   __restrict__ inds_2p,    // [R2]
    float*       __restrict__ y_out)      // [B, N_SPEC]
{
    __shared__ float ys[N_SPEC];  // staged input row
    __shared__ float yo[N_SPEC];  // accumulator row

    const int b   = blockIdx.x;
    const int tid = threadIdx.x;

    // Stage y row into LDS and zero the accumulator (float4 vectorized, coalesced).
    const float4* yrow = reinterpret_cast<const float4*>(y_in + (size_t)b * N_SPEC);
    float4* ys4 = reinterpret_cast<float4*>(ys);
    float4* yo4 = reinterpret_cast<float4*>(yo);
    #pragma unroll
    for (int i = tid; i < N_SPEC / 4; i += BLOCK) {
        ys4[i] = yrow[i];
        yo4[i] = make_float4(0.f, 0.f, 0.f, 0.f);
    }
    __syncthreads();

    // First-order reactions: coalesced rate read, LDS gather, LDS atomic scatter.
    const float* r1 = rates_1st + (size_t)b * R1;
    for (int r = tid; r < R1; r += BLOCK) {
        const float t = ys[inds_1r[r]] * r1[r];
        atomicAdd(&yo[inds_1p[r]], t);
    }

    // Second-order reactions.
    const float* r2 = rates_2nd + (size_t)b * R2;
    for (int r = tid; r < R2; r += BLOCK) {
        const int ia = inds_2r[2 * r];
        const int ib = inds_2r[2 * r + 1];
        const float t = ys[ia] * ys[ib] * r2[r];
        atomicAdd(&yo[inds_2p[r]], t);
    }
    __syncthreads();

    // Write the finished row (coalesced float4).
    float4* orow = reinterpret_cast<float4*>(y_out + (size_t)b * N_SPEC);
    #pragma unroll
    for (int i = tid; i < N_SPEC / 4; i += BLOCK) {
        orow[i] = yo4[i];
    }
}

extern "C" void kernel_launch(void* const* d_in, const int* in_sizes, int n_in,
                              void* d_out, int out_size, void* d_ws, size_t ws_size,
                              hipStream_t stream) {
    const float* y_in      = (const float*)d_in[0];
    const float* rates_1st = (const float*)d_in[1];
    const float* rates_2nd = (const float*)d_in[2];
    const int*   inds_1r   = (const int*)d_in[3];
    const int*   inds_1p   = (const int*)d_in[4];
    const int*   inds_2r   = (const int*)d_in[5];
    const int*   inds_2p   = (const int*)d_in[6];
    float*       y_out     = (float*)d_out;

    ReactionTerm_kernel<<<B_DIM, BLOCK, 0, stream>>>(
        y_in, rates_1st, rates_2nd, inds_1r, inds_1p, inds_2r, inds_2p, y_out);
}

// Round 2
// 529.550 us; speedup vs baseline: 1.0121x; 1.0121x over previous
//
#include <hip/hip_runtime.h>

// ReactionTerm: y_out[b, inds_1p[r]] += y_in[b, inds_1r[r]] * rates_1st[b, r]
//               y_out[b, inds_2p[r]] += y_in[b, i2r0[r]] * y_in[b, i2r1[r]] * rates_2nd[b, r]
// B=1024, N_SPEC=2048, R1=20000, R2=40000.
// One block per row; y row + accumulator in LDS (16 KB/block).
// Round 1 was latency-bound (VGPR=8, no ILP, 406 GB/s). This round:
//   - 4 reactions per thread per iteration via int4/float4 (4 indep chains in flight)
//   - BLOCK=512: 8 waves x 4 blocks/CU = 32 waves/CU = 100% occupancy, one full round.

#define B_DIM 1024
#define N_SPEC 2048
#define R1 20000
#define R2 40000
#define BLOCK 512

__global__ __launch_bounds__(BLOCK, 8) void ReactionTerm_kernel(
    const float* __restrict__ y_in,       // [B, N_SPEC]
    const float* __restrict__ rates_1st,  // [B, R1]
    const float* __restrict__ rates_2nd,  // [B, R2]
    const int*   __restrict__ inds_1r,    // [R1]
    const int*   __restrict__ inds_1p,    // [R1]
    const int*   __restrict__ inds_2r,    // [R2, 2]
    const int*   __restrict__ inds_2p,    // [R2]
    float*       __restrict__ y_out)      // [B, N_SPEC]
{
    __shared__ float ys[N_SPEC];  // staged input row
    __shared__ float yo[N_SPEC];  // accumulator row

    const int b   = blockIdx.x;
    const int tid = threadIdx.x;

    const float4* yrow = reinterpret_cast<const float4*>(y_in + (size_t)b * N_SPEC);
    float4* ys4 = reinterpret_cast<float4*>(ys);
    float4* yo4 = reinterpret_cast<float4*>(yo);
    #pragma unroll
    for (int i = tid; i < N_SPEC / 4; i += BLOCK) {
        ys4[i] = yrow[i];
        yo4[i] = make_float4(0.f, 0.f, 0.f, 0.f);
    }
    __syncthreads();

    // ---- First-order: 4 reactions/thread/iter. R1/4 = 5000 vec packs. ----
    {
        const int4*   i1r4 = reinterpret_cast<const int4*>(inds_1r);
        const int4*   i1p4 = reinterpret_cast<const int4*>(inds_1p);
        const float4* r14  = reinterpret_cast<const float4*>(rates_1st + (size_t)b * R1);
        for (int v = tid; v < R1 / 4; v += BLOCK) {
            const int4   ir = i1r4[v];
            const int4   ip = i1p4[v];
            const float4 rr = r14[v];
            const float t0 = ys[ir.x] * rr.x;
            const float t1 = ys[ir.y] * rr.y;
            const float t2 = ys[ir.z] * rr.z;
            const float t3 = ys[ir.w] * rr.w;
            atomicAdd(&yo[ip.x], t0);
            atomicAdd(&yo[ip.y], t1);
            atomicAdd(&yo[ip.z], t2);
            atomicAdd(&yo[ip.w], t3);
        }
    }

    // ---- Second-order: 4 reactions/thread/iter. R2/4 = 10000 vec packs. ----
    {
        const int4*   i2r4 = reinterpret_cast<const int4*>(inds_2r);  // int4 = 2 reactions
        const int4*   i2p4 = reinterpret_cast<const int4*>(inds_2p);
        const float4* r24  = reinterpret_cast<const float4*>(rates_2nd + (size_t)b * R2);
        for (int v = tid; v < R2 / 4; v += BLOCK) {
            const int4   ra = i2r4[2 * v];      // reactions 4v, 4v+1
            const int4   rb = i2r4[2 * v + 1];  // reactions 4v+2, 4v+3
            const int4   ip = i2p4[v];
            const float4 rr = r24[v];
            const float t0 = ys[ra.x] * ys[ra.y] * rr.x;
            const float t1 = ys[ra.z] * ys[ra.w] * rr.y;
            const float t2 = ys[rb.x] * ys[rb.y] * rr.z;
            const float t3 = ys[rb.z] * ys[rb.w] * rr.w;
            atomicAdd(&yo[ip.x], t0);
            atomicAdd(&yo[ip.y], t1);
            atomicAdd(&yo[ip.z], t2);
            atomicAdd(&yo[ip.w], t3);
        }
    }
    __syncthreads();

    float4* orow = reinterpret_cast<float4*>(y_out + (size_t)b * N_SPEC);
    #pragma unroll
    for (int i = tid; i < N_SPEC / 4; i += BLOCK) {
        orow[i] = yo4[i];
    }
}

extern "C" void kernel_launch(void* const* d_in, const int* in_sizes, int n_in,
                              void* d_out, int out_size, void* d_ws, size_t ws_size,
                              hipStream_t stream) {
    const float* y_in      = (const float*)d_in[0];
    const float* rates_1st = (const float*)d_in[1];
    const float* rates_2nd = (const float*)d_in[2];
    const int*   inds_1r   = (const int*)d_in[3];
    const int*   inds_1p   = (const int*)d_in[4];
    const int*   inds_2r   = (const int*)d_in[5];
    const int*   inds_2p   = (const int*)d_in[6];
    float*       y_out     = (float*)d_out;

    ReactionTerm_kernel<<<B_DIM, BLOCK, 0, stream>>>(
        y_in, rates_1st, rates_2nd, inds_1r, inds_1p, inds_2r, inds_2p, y_out);
}

// Round 3
// 529.078 us; speedup vs baseline: 1.0130x; 1.0009x over previous
//
#include <hip/hip_runtime.h>

// ReactionTerm: y_out[b, inds_1p[r]] += y_in[b, inds_1r[r]] * rates_1st[b, r]
//               y_out[b, inds_2p[r]] += y_in[b, i2r0[r]] * y_in[b, i2r1[r]] * rates_2nd[b, r]
// B=1024, N_SPEC=2048, R1=20000, R2=40000.
// One block per row; y row + accumulator in LDS (16 KB/block).
// R2 post-mortem: latency-bound in the LDS path; hypothesis = atomicAdd(shared
// float) lowers to a CAS retry loop. This round: native ds_add_f32 via
// unsafeAtomicAdd + software-pipelined global loads (prefetch v+1 before LDS
// ops of v).

#define B_DIM 1024
#define N_SPEC 2048
#define R1 20000
#define R2 40000
#define BLOCK 512
#define P1 (R1 / 4)   // 5000 int4/float4 packs
#define P2 (R2 / 4)   // 10000 packs

__device__ __forceinline__ void lds_fadd(float* addr, float v) {
    // unsafeAtomicAdd emits the native no-return LDS fadd (ds_add_f32) on
    // gfx90a+ for __shared__ pointers; atomicAdd may lower to a CAS loop.
    unsafeAtomicAdd(addr, v);
}

__global__ __launch_bounds__(BLOCK, 8) void ReactionTerm_kernel(
    const float* __restrict__ y_in,       // [B, N_SPEC]
    const float* __restrict__ rates_1st,  // [B, R1]
    const float* __restrict__ rates_2nd,  // [B, R2]
    const int*   __restrict__ inds_1r,    // [R1]
    const int*   __restrict__ inds_1p,    // [R1]
    const int*   __restrict__ inds_2r,    // [R2, 2]
    const int*   __restrict__ inds_2p,    // [R2]
    float*       __restrict__ y_out)      // [B, N_SPEC]
{
    __shared__ float ys[N_SPEC];  // staged input row
    __shared__ float yo[N_SPEC];  // accumulator row

    const int b   = blockIdx.x;
    const int tid = threadIdx.x;

    const float4* yrow = reinterpret_cast<const float4*>(y_in + (size_t)b * N_SPEC);
    float4* ys4 = reinterpret_cast<float4*>(ys);
    float4* yo4 = reinterpret_cast<float4*>(yo);
    #pragma unroll
    for (int i = tid; i < N_SPEC / 4; i += BLOCK) {
        ys4[i] = yrow[i];
        yo4[i] = make_float4(0.f, 0.f, 0.f, 0.f);
    }
    __syncthreads();

    // ---- First-order: 4 reactions/thread/iter, software-pipelined. ----
    {
        const int4*   i1r4 = reinterpret_cast<const int4*>(inds_1r);
        const int4*   i1p4 = reinterpret_cast<const int4*>(inds_1p);
        const float4* r14  = reinterpret_cast<const float4*>(rates_1st + (size_t)b * R1);
        int v = tid;                      // tid < 512 <= P1, always one iter
        int4   ir = i1r4[v];
        int4   ip = i1p4[v];
        float4 rr = r14[v];
        for (;;) {
            const int  vn   = v + BLOCK;
            const bool more = vn < P1;
            int4 irn, ipn; float4 rrn;
            if (more) { irn = i1r4[vn]; ipn = i1p4[vn]; rrn = r14[vn]; }
            lds_fadd(&yo[ip.x], ys[ir.x] * rr.x);
            lds_fadd(&yo[ip.y], ys[ir.y] * rr.y);
            lds_fadd(&yo[ip.z], ys[ir.z] * rr.z);
            lds_fadd(&yo[ip.w], ys[ir.w] * rr.w);
            if (!more) break;
            ir = irn; ip = ipn; rr = rrn; v = vn;
        }
    }

    // ---- Second-order: 4 reactions/thread/iter, software-pipelined. ----
    {
        const int4*   i2r4 = reinterpret_cast<const int4*>(inds_2r);  // int4 = 2 reactions
        const int4*   i2p4 = reinterpret_cast<const int4*>(inds_2p);
        const float4* r24  = reinterpret_cast<const float4*>(rates_2nd + (size_t)b * R2);
        int v = tid;                      // tid < 512 <= P2, always one iter
        int4   ra = i2r4[2 * v];
        int4   rb = i2r4[2 * v + 1];
        int4   ip = i2p4[v];
        float4 rr = r24[v];
        for (;;) {
            const int  vn   = v + BLOCK;
            const bool more = vn < P2;
            int4 ran, rbn, ipn; float4 rrn;
            if (more) {
                ran = i2r4[2 * vn];
                rbn = i2r4[2 * vn + 1];
                ipn = i2p4[vn];
                rrn = r24[vn];
            }
            lds_fadd(&yo[ip.x], ys[ra.x] * ys[ra.y] * rr.x);
            lds_fadd(&yo[ip.y], ys[ra.z] * ys[ra.w] * rr.y);
            lds_fadd(&yo[ip.z], ys[rb.x] * ys[rb.y] * rr.z);
            lds_fadd(&yo[ip.w], ys[rb.z] * ys[rb.w] * rr.w);
            if (!more) break;
            ra = ran; rb = rbn; ip = ipn; rr = rrn; v = vn;
        }
    }
    __syncthreads();

    float4* orow = reinterpret_cast<float4*>(y_out + (size_t)b * N_SPEC);
    #pragma unroll
    for (int i = tid; i < N_SPEC / 4; i += BLOCK) {
        orow[i] = yo4[i];
    }
}

extern "C" void kernel_launch(void* const* d_in, const int* in_sizes, int n_in,
                              void* d_out, int out_size, void* d_ws, size_t ws_size,
                              hipStream_t stream) {
    const float* y_in      = (const float*)d_in[0];
    const float* rates_1st = (const float*)d_in[1];
    const float* rates_2nd = (const float*)d_in[2];
    const int*   inds_1r   = (const int*)d_in[3];
    const int*   inds_1p   = (const int*)d_in[4];
    const int*   inds_2r   = (const int*)d_in[5];
    const int*   inds_2p   = (const int*)d_in[6];
    float*       y_out     = (float*)d_out;

    ReactionTerm_kernel<<<B_DIM, BLOCK, 0, stream>>>(
        y_in, rates_1st, rates_2nd, inds_1r, inds_1p, inds_2r, inds_2p, y_out);
}